// Round 6
// baseline (319.044 us; speedup 1.0000x reference)
//
#include <hip/hip_runtime.h>
#include <stdint.h>

#define B_TOT 2048
#define H_DIM 4096
#define R_DIM 64

#define X_ELEMS  (B_TOT * H_DIM)           // 8388608
#define W_ELEMS  (B_TOT)                   // 2048
#define A_ELEMS  (64 * H_DIM * R_DIM)      // 16777216

// Correctness probe, float32 in / float32 out (fp16 reference promotes to f32
// on device per harness contract: "bfloat16 -> __hip_bfloat16*, else float*").
// One block per sample b: out[b][r] = sum_h x[b][h] * A[wids[b]][h][r].
// Thread t = (q, r): q = t>>6 covers h in [q*1024, (q+1)*1024), r = t&63.
__global__ __launch_bounds__(256)
void k_naive_f32(const float* __restrict__ x, const int* __restrict__ wids,
                 const float* __restrict__ A, float* __restrict__ out) {
  __shared__ float red[256];
  const int b = blockIdx.x;
  const int t = threadIdx.x;
  const int r = t & 63;
  const int q = t >> 6;
  const int a = wids[b];

  const float* xrow = x + (size_t)b * H_DIM;
  const float* Aad  = A + (size_t)a * H_DIM * R_DIM + r;

  float acc = 0.f;
  const int h0 = q * (H_DIM / 4), h1 = h0 + (H_DIM / 4);
  for (int h = h0; h < h1; ++h) {
    acc += xrow[h] * Aad[(size_t)h * R_DIM];
  }

  red[t] = acc;
  __syncthreads();
  if (t < 64) {
    float s = red[t] + red[t + 64] + red[t + 128] + red[t + 192];
    out[(size_t)b * R_DIM + t] = s;
  }
}

extern "C" void kernel_launch(void* const* d_in, const int* in_sizes, int n_in,
                              void* d_out, int out_size, void* d_ws, size_t ws_size,
                              hipStream_t stream) {
  // Identify inputs by element count — robust to any ordering.
  const void* px = nullptr;
  const void* pw = nullptr;
  const void* pa = nullptr;
  for (int i = 0; i < n_in; ++i) {
    if (in_sizes[i] == X_ELEMS) px = d_in[i];
    else if (in_sizes[i] == W_ELEMS) pw = d_in[i];
    else if (in_sizes[i] == A_ELEMS) pa = d_in[i];
  }
  if (!px || !pw || !pa) { px = d_in[0]; pw = d_in[1]; pa = d_in[2]; }

  const float* x    = (const float*)px;
  const int*   wids = (const int*)pw;
  const float* A    = (const float*)pa;
  float* out = (float*)d_out;
  (void)d_ws; (void)ws_size; (void)out_size;

  k_naive_f32<<<dim3(B_TOT), dim3(256), 0, stream>>>(x, wids, A, out);
}

// Round 7
// 114.006 us; speedup vs baseline: 2.7985x; 2.7985x over previous
//
#include <hip/hip_runtime.h>
#include <stdint.h>

#define B_TOT 2048
#define H_DIM 4096
#define R_DIM 64
#define NA_DIM 64
#define GS 8            // samples per group
#define SPLIT 8         // slots (blocks) per adapter
#define CH 128          // k per chunk
#define NCH (H_DIM/CH)  // 32
#define XSTR 132        // padded x row stride in f32 (bank-shift 8/2rows)

#define X_ELEMS (B_TOT*H_DIM)        // 8388608
#define W_ELEMS (B_TOT)              // 2048
#define A_ELEMS (NA_DIM*H_DIM*R_DIM) // 16777216

#define FMA4(acc, av, xs) { acc[0] += (av).x*(xs); acc[1] += (av).y*(xs); \
                            acc[2] += (av).z*(xs); acc[3] += (av).w*(xs); }

// Block (adapter a, slot): wave 0 ballot-scans wids -> ordered sample list.
// Slot handles 8-sample groups g = slot, slot+8, ... For each group, loop 32
// k-chunks: stage A[128][64] (32 KB) + x[8][128] in LDS; 4 waves split the
// chunk's k 4-ways; lane tile = 2 samples x 4 r; cross-wave reduce per group.
__global__ __launch_bounds__(256, 2)
void k_lora_f32_binned(const float* __restrict__ x, const int* __restrict__ wids,
                       const float* __restrict__ A, float* __restrict__ out) {
  __shared__ __align__(16) float AL[CH * R_DIM];        // 32 KB [k][r]
  __shared__ __align__(16) float XT[GS * XSTR];         // 4.2 KB [s][k] padded
  __shared__ __align__(16) float RS[3 * GS * R_DIM];    // 6 KB [w-1][s][r]
  __shared__ uint16_t sbin[B_TOT];                      // 4 KB ordered indices
  __shared__ int sn;

  const int bx = blockIdx.x;
  const int a = bx >> 3, slot = bx & 7;
  const int t = threadIdx.x;
  const int w = t >> 6, l = t & 63;

  // ---- wave 0: ballot-scan wids -> ordered bin list ----
  if (w == 0) {
    int v[32];
#pragma unroll
    for (int i = 0; i < 32; ++i) v[i] = wids[i * 64 + l];
    int cnt = 0;
#pragma unroll
    for (int i = 0; i < 32; ++i) {
      bool hit = (v[i] == a);
      unsigned long long m = __ballot(hit);
      if (hit) {
        int rank = __popcll(m & ((1ull << l) - 1ull));
        sbin[cnt + rank] = (uint16_t)(i * 64 + l);
      }
      cnt += __popcll(m);
    }
    if (l == 0) sn = cnt;
  }
  __syncthreads();
  const int n = sn;

  const int sp = l >> 4;   // s-pair: samples 2sp, 2sp+1
  const int rq = l & 15;   // r-quad: r = 4rq .. 4rq+3

  for (int g = slot; g * GS < n; g += SPLIT) {
    const int base = g * GS;
    float acc0[4] = {0.f, 0.f, 0.f, 0.f};
    float acc1[4] = {0.f, 0.f, 0.f, 0.f};

    for (int c = 0; c < NCH; ++c) {
      __syncthreads();   // AL/XT reusable (prev chunk / prev group done)

      // stage A chunk: 8192 f32, coalesced float4 x 8 per thread
      const float* Ab = A + ((size_t)a * H_DIM + (size_t)c * CH) * R_DIM;
#pragma unroll
      for (int i = 0; i < 8; ++i) {
        int o4 = (i * 256 + t) * 4;
        *(float4*)&AL[o4] = *(const float4*)&Ab[o4];
      }
      // stage x tile: 8 samples x 128 k, one float4 per thread
      {
        int s = t >> 5, k4 = t & 31;
        int sidx = base + s; if (sidx > n - 1) sidx = n - 1;
        const float* xr = x + (size_t)sbin[sidx] * H_DIM + (size_t)c * CH;
        *(float4*)&XT[s * XSTR + k4 * 4] = *(const float4*)&xr[k4 * 4];
      }
      __syncthreads();

      // compute: wave w covers chunk-k [w*32, w*32+32)
      const float* Ap = AL + (w * 32) * R_DIM + rq * 4;
      const float* X0 = XT + (2 * sp) * XSTR + w * 32;
      const float* X1 = X0 + XSTR;
#pragma unroll
      for (int i4 = 0; i4 < 8; ++i4) {
        float4 xa = *(const float4*)(X0 + i4 * 4);
        float4 xb = *(const float4*)(X1 + i4 * 4);
        float4 a0 = *(const float4*)(Ap + (i4 * 4 + 0) * R_DIM);
        float4 a1 = *(const float4*)(Ap + (i4 * 4 + 1) * R_DIM);
        float4 a2 = *(const float4*)(Ap + (i4 * 4 + 2) * R_DIM);
        float4 a3 = *(const float4*)(Ap + (i4 * 4 + 3) * R_DIM);
        FMA4(acc0, a0, xa.x); FMA4(acc0, a1, xa.y);
        FMA4(acc0, a2, xa.z); FMA4(acc0, a3, xa.w);
        FMA4(acc1, a0, xb.x); FMA4(acc1, a1, xb.y);
        FMA4(acc1, a2, xb.z); FMA4(acc1, a3, xb.w);
      }
    }

    // ---- cross-wave reduce, wave 0 stores ----
    if (w > 0) {
      float* dst = RS + (size_t)(w - 1) * (GS * R_DIM);
      *(float4*)(dst + (2 * sp) * R_DIM + rq * 4) =
          make_float4(acc0[0], acc0[1], acc0[2], acc0[3]);
      *(float4*)(dst + (2 * sp + 1) * R_DIM + rq * 4) =
          make_float4(acc1[0], acc1[1], acc1[2], acc1[3]);
    }
    __syncthreads();
    if (w == 0) {
#pragma unroll
      for (int j = 0; j < 2; ++j) {
        int sidx = base + 2 * sp + j;
        if (sidx < n) {
          float v0 = j ? acc1[0] : acc0[0];
          float v1 = j ? acc1[1] : acc0[1];
          float v2 = j ? acc1[2] : acc0[2];
          float v3 = j ? acc1[3] : acc0[3];
#pragma unroll
          for (int k = 0; k < 3; ++k) {
            float4 p = *(const float4*)(RS + (size_t)k * (GS * R_DIM) +
                                        (2 * sp + j) * R_DIM + rq * 4);
            v0 += p.x; v1 += p.y; v2 += p.z; v3 += p.w;
          }
          *(float4*)&out[(size_t)sbin[sidx] * R_DIM + rq * 4] =
              make_float4(v0, v1, v2, v3);
        }
      }
    }
    __syncthreads();   // RS safe to reuse next group
  }
}

extern "C" void kernel_launch(void* const* d_in, const int* in_sizes, int n_in,
                              void* d_out, int out_size, void* d_ws, size_t ws_size,
                              hipStream_t stream) {
  // Identify inputs by element count — robust to any ordering.
  const void* px = nullptr; const void* pw = nullptr; const void* pa = nullptr;
  for (int i = 0; i < n_in; ++i) {
    if (in_sizes[i] == X_ELEMS) px = d_in[i];
    else if (in_sizes[i] == W_ELEMS) pw = d_in[i];
    else if (in_sizes[i] == A_ELEMS) pa = d_in[i];
  }
  if (!px || !pw || !pa) { px = d_in[0]; pw = d_in[1]; pa = d_in[2]; }

  const float* x    = (const float*)px;
  const int*   wids = (const int*)pw;
  const float* A    = (const float*)pa;
  float* out = (float*)d_out;
  (void)d_ws; (void)ws_size; (void)out_size;

  k_lora_f32_binned<<<dim3(NA_DIM * SPLIT), dim3(256), 0, stream>>>(x, wids, A, out);
}

// Round 8
// 59.239 us; speedup vs baseline: 5.3857x; 1.9245x over previous
//
#include <hip/hip_runtime.h>
#include <stdint.h>

#define B_TOT 2048
#define H_DIM 4096
#define R_DIM 64
#define NA_DIM 64
#define GS 32           // samples per group
#define CH 128          // k per staged chunk
#define XSTR 132        // x-tile row stride (f32 words): 132%32=4 -> conflict-free
#define RSTR 68         // reduce-scratch row stride: 68%32=4 -> conflict-free

#define X_ELEMS (B_TOT*H_DIM)        // 8388608
#define W_ELEMS (B_TOT)              // 2048
#define A_ELEMS (NA_DIM*H_DIM*R_DIM) // 16777216

// Block (adapter a, k-slice ks): owns k range [ks*KS, (ks+1)*KS).
// Wave 0 ballot-scans wids -> ordered sample list (deterministic).
// Per 32-sample group: loop KS/CH chunks {stage A[128][64] 32KB + x[32][128];
// 4 waves split chunk-k 4-ways; lane = (sg = l>>4, rq = l&15) holds
// acc[8][4] for samples s = sg+4j}. Cross-wave LDS reduce once per group,
// wave 0 writes the slice partial (or out directly when NS==1).
template<int NS>
__global__ __launch_bounds__(256, 2)
void k_lora_slice(const float* __restrict__ x, const int* __restrict__ wids,
                  const float* __restrict__ A, float* __restrict__ part) {
  constexpr int KS = H_DIM / NS;   // k per slice
  constexpr int NCHB = KS / CH;    // chunks per block
  __shared__ __align__(16) float AL[CH * R_DIM];      // 32 KB [k][r]
  __shared__ __align__(16) float XT[GS * XSTR];       // 16.5 KB [s][k] padded
  __shared__ __align__(16) float RS[3 * GS * RSTR];   // 25.5 KB [w-1][s][r] padded
  __shared__ uint16_t sbin[B_TOT];                    // 4 KB
  __shared__ int sn;

  const int bx = blockIdx.x;
  const int a = bx / NS, ks = bx % NS;
  const int t = threadIdx.x;
  const int w = t >> 6, l = t & 63;

  // ---- wave 0: ballot-scan wids -> ordered bin list ----
  if (w == 0) {
    int v[32];
#pragma unroll
    for (int i = 0; i < 32; ++i) v[i] = wids[i * 64 + l];
    int cnt = 0;
#pragma unroll
    for (int i = 0; i < 32; ++i) {
      bool hit = (v[i] == a);
      unsigned long long m = __ballot(hit);
      if (hit) {
        int rank = __popcll(m & ((1ull << l) - 1ull));
        sbin[cnt + rank] = (uint16_t)(i * 64 + l);
      }
      cnt += __popcll(m);
    }
    if (l == 0) sn = cnt;
  }
  __syncthreads();
  const int n = sn;

  const int rq = l & 15;   // r-quad: r = rq*4 .. rq*4+3
  const int sg = l >> 4;   // sample-group: s = sg + 4j

  for (int g = 0; g * GS < n; ++g) {
    const int base = g * GS;
    float acc[8][4];
#pragma unroll
    for (int j = 0; j < 8; ++j)
#pragma unroll
      for (int r = 0; r < 4; ++r) acc[j][r] = 0.f;

    for (int c = 0; c < NCHB; ++c) {
      __syncthreads();   // AL/XT safe to overwrite

      // stage A chunk: 8192 f32, float4 x 8 per thread, coalesced
      const float* Ab = A + ((size_t)a * H_DIM + ks * KS + c * CH) * R_DIM;
#pragma unroll
      for (int i = 0; i < 8; ++i) {
        int o4 = (i * 256 + t) * 4;
        *(float4*)&AL[o4] = *(const float4*)&Ab[o4];
      }
      // stage x tile: 32 samples x 128 k, 4 float4 per thread
      {
        int s = t >> 3, q = t & 7;
        int sidx = base + s; if (sidx > n - 1) sidx = n - 1;
        const float* xr = x + (size_t)sbin[sidx] * H_DIM + ks * KS + c * CH;
#pragma unroll
        for (int m = 0; m < 4; ++m) {
          int k4 = q + m * 8;
          *(float4*)&XT[s * XSTR + k4 * 4] = *(const float4*)&xr[k4 * 4];
        }
      }
      __syncthreads();

      // compute: wave w covers chunk-k [w*32, w*32+32)
      const float* Ap = AL + (w * 32) * R_DIM + rq * 4;
      const float* Xp = XT + sg * XSTR + w * 32;
#pragma unroll
      for (int kq = 0; kq < 8; ++kq) {
        float4 a0 = *(const float4*)(Ap + (kq * 4 + 0) * R_DIM);
        float4 a1 = *(const float4*)(Ap + (kq * 4 + 1) * R_DIM);
        float4 a2 = *(const float4*)(Ap + (kq * 4 + 2) * R_DIM);
        float4 a3 = *(const float4*)(Ap + (kq * 4 + 3) * R_DIM);
#pragma unroll
        for (int j = 0; j < 8; ++j) {
          float4 xv = *(const float4*)(Xp + (4 * j) * XSTR + kq * 4);
          acc[j][0] += xv.x * a0.x; acc[j][1] += xv.x * a0.y;
          acc[j][2] += xv.x * a0.z; acc[j][3] += xv.x * a0.w;
          acc[j][0] += xv.y * a1.x; acc[j][1] += xv.y * a1.y;
          acc[j][2] += xv.y * a1.z; acc[j][3] += xv.y * a1.w;
          acc[j][0] += xv.z * a2.x; acc[j][1] += xv.z * a2.y;
          acc[j][2] += xv.z * a2.z; acc[j][3] += xv.z * a2.w;
          acc[j][0] += xv.w * a3.x; acc[j][1] += xv.w * a3.y;
          acc[j][2] += xv.w * a3.z; acc[j][3] += xv.w * a3.w;
        }
      }
    }

    // ---- cross-wave reduce (once per group), wave 0 stores ----
    if (w > 0) {
      float* dst = RS + (size_t)(w - 1) * (GS * RSTR);
#pragma unroll
      for (int j = 0; j < 8; ++j)
        *(float4*)(dst + (sg + 4 * j) * RSTR + rq * 4) =
            make_float4(acc[j][0], acc[j][1], acc[j][2], acc[j][3]);
    }
    __syncthreads();
    if (w == 0) {
#pragma unroll
      for (int j = 0; j < 8; ++j) {
        int s = sg + 4 * j;
        int sidx = base + s;
        if (sidx < n) {
          float v0 = acc[j][0], v1 = acc[j][1], v2 = acc[j][2], v3 = acc[j][3];
#pragma unroll
          for (int k = 0; k < 3; ++k) {
            const float* src = RS + (size_t)k * (GS * RSTR) + s * RSTR + rq * 4;
            v0 += src[0]; v1 += src[1]; v2 += src[2]; v3 += src[3];
          }
          size_t row = (size_t)(NS == 1 ? 0 : ks) * B_TOT + sbin[sidx];
          *(float4*)&part[row * R_DIM + rq * 4] = make_float4(v0, v1, v2, v3);
        }
      }
    }
    // next group's first chunk-top __syncthreads orders RS reuse
  }
}

__global__ __launch_bounds__(256)
void k_reduce8(const float* __restrict__ part, float* __restrict__ out) {
  int t = blockIdx.x * 256 + threadIdx.x;   // 32768 threads, one float4 each
  size_t o = (size_t)t * 4;
  float v0 = 0.f, v1 = 0.f, v2 = 0.f, v3 = 0.f;
#pragma unroll
  for (int p = 0; p < 8; ++p) {
    float4 q = *(const float4*)&part[(size_t)p * (B_TOT * R_DIM) + o];
    v0 += q.x; v1 += q.y; v2 += q.z; v3 += q.w;
  }
  *(float4*)&out[o] = make_float4(v0, v1, v2, v3);
}

extern "C" void kernel_launch(void* const* d_in, const int* in_sizes, int n_in,
                              void* d_out, int out_size, void* d_ws, size_t ws_size,
                              hipStream_t stream) {
  // Identify inputs by element count — robust to any ordering.
  const void* px = nullptr; const void* pw = nullptr; const void* pa = nullptr;
  for (int i = 0; i < n_in; ++i) {
    if (in_sizes[i] == X_ELEMS) px = d_in[i];
    else if (in_sizes[i] == W_ELEMS) pw = d_in[i];
    else if (in_sizes[i] == A_ELEMS) pa = d_in[i];
  }
  if (!px || !pw || !pa) { px = d_in[0]; pw = d_in[1]; pa = d_in[2]; }

  const float* x    = (const float*)px;
  const int*   wids = (const int*)pw;
  const float* A    = (const float*)pa;
  float* out = (float*)d_out;
  (void)out_size;

  const size_t need = (size_t)8 * B_TOT * R_DIM * sizeof(float);  // 4 MB
  if (ws_size >= need) {
    float* part = (float*)d_ws;
    k_lora_slice<8><<<dim3(NA_DIM * 8), dim3(256), 0, stream>>>(x, wids, A, part);
    k_reduce8<<<dim3(128), dim3(256), 0, stream>>>(part, out);
  } else {
    // Fallback: single slice writes out directly (no workspace).
    k_lora_slice<1><<<dim3(NA_DIM), dim3(256), 0, stream>>>(x, wids, A, out);
  }
}

// Round 9
// 54.874 us; speedup vs baseline: 5.8141x; 1.0795x over previous
//
#include <hip/hip_runtime.h>
#include <stdint.h>

#define B_TOT 2048
#define H_DIM 4096
#define R_DIM 64
#define NA_DIM 64
#define GS 32              // samples per group
#define CH 64              // k per staged chunk
#define XPAD 68            // XT row stride (f32 words), conflict-free
#define X_ELEMS (B_TOT*H_DIM)        // 8388608
#define W_ELEMS (B_TOT)              // 2048
#define A_ELEMS (NA_DIM*H_DIM*R_DIM) // 16777216

// async global->LDS, 16 B per lane; dest must be linear (base + lane*16)
#define GLDS16(gp, lp) __builtin_amdgcn_global_load_lds(                         \
    (const __attribute__((address_space(1))) uint32_t*)(const void*)(gp),        \
    (__attribute__((address_space(3))) uint32_t*)(lp), 16, 0, 0)

// Block (adapter a, k-slice ks): owns k in [ks*KS, (ks+1)*KS).
// Wave 0 ballot-scans wids -> ordered sample list (deterministic).
// Per 32-sample group: NCHB=KS/64 chunks, software-pipelined:
//   barrier; issue glds(A,c+1)+load x-regs(c+1); compute(c); ds_write x(c+1)
// AL is double-buffered (2x16KB) and aliased as reduce scratch in the epilogue.
template<int NS>
__global__ __launch_bounds__(256, 3)
void k_lora_pipe(const float* __restrict__ x, const int* __restrict__ wids,
                 const float* __restrict__ A, float* __restrict__ part) {
  constexpr int KS = H_DIM / NS;   // k per slice
  constexpr int NCHB = KS / CH;    // chunks per block
  __shared__ __align__(16) float AL[2 * CH * R_DIM];  // 32 KB dbuf [k][r]
  __shared__ __align__(16) float XT[2 * GS * XPAD];   // 17 KB dbuf [s][k] padded
  __shared__ uint16_t sbin[B_TOT];                    // 4 KB
  __shared__ int sn;
  float* RS = AL;  // epilogue alias: [3][GS][XPAD] = 26 KB <= 32 KB

  const int bx = blockIdx.x;
  const int a = bx / NS, ks = bx % NS;
  const int t = threadIdx.x;
  const int w = t >> 6, l = t & 63;

  const float* Aslice = A + ((size_t)a * H_DIM + (size_t)ks * KS) * R_DIM;

  // ---- issue A chunk-0 async staging (independent of sbin) ----
  {
    const float* src = Aslice;
    float* dst = AL;
#pragma unroll
    for (int i = 0; i < 4; ++i)
      GLDS16(src + i * 1024 + t * 4, dst + i * 1024 + t * 4);
  }

  // ---- wave 0: ballot-scan wids -> ordered bin list ----
  if (w == 0) {
    int v[32];
#pragma unroll
    for (int i = 0; i < 32; ++i) v[i] = wids[i * 64 + l];
    int cnt = 0;
#pragma unroll
    for (int i = 0; i < 32; ++i) {
      bool hit = (v[i] == a);
      unsigned long long m = __ballot(hit);
      if (hit) {
        int rank = __popcll(m & ((1ull << l) - 1ull));
        sbin[cnt + rank] = (uint16_t)(i * 64 + l);
      }
      cnt += __popcll(m);
    }
    if (l == 0) sn = cnt;
  }
  __syncthreads();   // sbin ready (also drains chunk-0 glds; scan overlapped it)
  const int n = sn;
  if (n == 0) return;

  const int s_st = t >> 3;        // staging: sample slot 0..31
  const int k8 = (t & 7) * 8;     // staging: k offset within chunk
  const int rq = l & 15;          // compute: r-quad
  const int sg = l >> 4;          // compute: sample-group (s = sg+4j)

  for (int g = 0; g * GS < n; ++g) {
    const int base = g * GS;
    int sidx0 = base + s_st; if (sidx0 > n - 1) sidx0 = n - 1;
    const float* xrow = x + (size_t)sbin[sidx0] * H_DIM + (size_t)ks * KS;

    float acc[8][4];
#pragma unroll
    for (int j = 0; j < 8; ++j)
#pragma unroll
      for (int r = 0; r < 4; ++r) acc[j][r] = 0.f;

    if (g > 0) {   // re-issue A chunk-0 (AL buf0 was reduce scratch)
      const float* src = Aslice;
#pragma unroll
      for (int i = 0; i < 4; ++i)
        GLDS16(src + i * 1024 + t * 4, AL + i * 1024 + t * 4);
    }
    // x chunk-0 -> regs -> XT buf0
    float4 xr0 = *(const float4*)(xrow + k8);
    float4 xr1 = *(const float4*)(xrow + k8 + 4);
    {
      float* d = XT + s_st * XPAD + k8;
      *(float4*)d = xr0; *(float4*)(d + 4) = xr1;
    }

    for (int c = 0; c < NCHB; ++c) {
      __syncthreads();   // glds(c) drained + XT(c) writes visible
      const int cb = c & 1;
      if (c + 1 < NCHB) {
        const int nb = (c + 1) & 1;
        const float* src = Aslice + (size_t)(c + 1) * CH * R_DIM;
        float* dst = AL + nb * (CH * R_DIM);
#pragma unroll
        for (int i = 0; i < 4; ++i)
          GLDS16(src + i * 1024 + t * 4, dst + i * 1024 + t * 4);
        xr0 = *(const float4*)(xrow + (size_t)(c + 1) * CH + k8);
        xr1 = *(const float4*)(xrow + (size_t)(c + 1) * CH + k8 + 4);
      }
      // compute chunk c: wave w covers chunk-k [w*16, w*16+16)
      const float* Ap = AL + cb * (CH * R_DIM) + (w * 16) * R_DIM + rq * 4;
      const float* Xp = XT + cb * (GS * XPAD) + sg * XPAD + w * 16;
#pragma unroll
      for (int kq = 0; kq < 4; ++kq) {
        float4 a0 = *(const float4*)(Ap + (kq * 4 + 0) * R_DIM);
        float4 a1 = *(const float4*)(Ap + (kq * 4 + 1) * R_DIM);
        float4 a2 = *(const float4*)(Ap + (kq * 4 + 2) * R_DIM);
        float4 a3 = *(const float4*)(Ap + (kq * 4 + 3) * R_DIM);
#pragma unroll
        for (int j = 0; j < 8; ++j) {
          float4 xv = *(const float4*)(Xp + (4 * j) * XPAD + kq * 4);
          acc[j][0] += xv.x * a0.x; acc[j][1] += xv.x * a0.y;
          acc[j][2] += xv.x * a0.z; acc[j][3] += xv.x * a0.w;
          acc[j][0] += xv.y * a1.x; acc[j][1] += xv.y * a1.y;
          acc[j][2] += xv.y * a1.z; acc[j][3] += xv.y * a1.w;
          acc[j][0] += xv.z * a2.x; acc[j][1] += xv.z * a2.y;
          acc[j][2] += xv.z * a2.z; acc[j][3] += xv.z * a2.w;
          acc[j][0] += xv.w * a3.x; acc[j][1] += xv.w * a3.y;
          acc[j][2] += xv.w * a3.z; acc[j][3] += xv.w * a3.w;
        }
      }
      if (c + 1 < NCHB) {   // XT(c+1) write: its buf last read in compute(c-1)
        float* d = XT + ((c + 1) & 1) * (GS * XPAD) + s_st * XPAD + k8;
        *(float4*)d = xr0; *(float4*)(d + 4) = xr1;
      }
    }

    // ---- cross-wave reduce (RS aliases AL; all compute done) ----
    __syncthreads();
    if (w > 0) {
      float* dst = RS + (size_t)(w - 1) * (GS * XPAD);
#pragma unroll
      for (int j = 0; j < 8; ++j)
        *(float4*)(dst + (sg + 4 * j) * XPAD + rq * 4) =
            make_float4(acc[j][0], acc[j][1], acc[j][2], acc[j][3]);
    }
    __syncthreads();
    if (w == 0) {
#pragma unroll
      for (int j = 0; j < 8; ++j) {
        int s = sg + 4 * j;
        int sidx = base + s;
        if (sidx < n) {
          float v0 = acc[j][0], v1 = acc[j][1], v2 = acc[j][2], v3 = acc[j][3];
#pragma unroll
          for (int k = 0; k < 3; ++k) {
            const float* srs = RS + (size_t)k * (GS * XPAD) + s * XPAD + rq * 4;
            v0 += srs[0]; v1 += srs[1]; v2 += srs[2]; v3 += srs[3];
          }
          size_t row = (size_t)(NS == 1 ? 0 : ks) * B_TOT + sbin[sidx];
          *(float4*)&part[row * R_DIM + rq * 4] = make_float4(v0, v1, v2, v3);
        }
      }
    }
    if ((g + 1) * GS < n) __syncthreads();  // RS reads done before next stage_A
  }
}

__global__ __launch_bounds__(256)
void k_reduce8(const float* __restrict__ part, float* __restrict__ out) {
  int t = blockIdx.x * 256 + threadIdx.x;   // 32768 threads, one float4 each
  size_t o = (size_t)t * 4;
  float v0 = 0.f, v1 = 0.f, v2 = 0.f, v3 = 0.f;
#pragma unroll
  for (int p = 0; p < 8; ++p) {
    float4 q = *(const float4*)&part[(size_t)p * (B_TOT * R_DIM) + o];
    v0 += q.x; v1 += q.y; v2 += q.z; v3 += q.w;
  }
  *(float4*)&out[o] = make_float4(v0, v1, v2, v3);
}

extern "C" void kernel_launch(void* const* d_in, const int* in_sizes, int n_in,
                              void* d_out, int out_size, void* d_ws, size_t ws_size,
                              hipStream_t stream) {
  // Identify inputs by element count — robust to any ordering.
  const void* px = nullptr; const void* pw = nullptr; const void* pa = nullptr;
  for (int i = 0; i < n_in; ++i) {
    if (in_sizes[i] == X_ELEMS) px = d_in[i];
    else if (in_sizes[i] == W_ELEMS) pw = d_in[i];
    else if (in_sizes[i] == A_ELEMS) pa = d_in[i];
  }
  if (!px || !pw || !pa) { px = d_in[0]; pw = d_in[1]; pa = d_in[2]; }

  const float* x    = (const float*)px;
  const int*   wids = (const int*)pw;
  const float* A    = (const float*)pa;
  float* out = (float*)d_out;
  (void)out_size;

  const size_t need = (size_t)8 * B_TOT * R_DIM * sizeof(float);  // 4 MB
  if (ws_size >= need) {
    float* part = (float*)d_ws;
    k_lora_pipe<8><<<dim3(NA_DIM * 8), dim3(256), 0, stream>>>(x, wids, A, part);
    k_reduce8<<<dim3(128), dim3(256), 0, stream>>>(part, out);
  } else {
    k_lora_pipe<1><<<dim3(NA_DIM), dim3(256), 0, stream>>>(x, wids, A, out);
  }
}